// Round 8
// baseline (128.982 us; speedup 1.0000x reference)
//
#include <hip/hip_runtime.h>
#include <hip/hip_bf16.h>
#include <math.h>

#define BB 16
#define HH 256
#define WW 256

// ws layout in floats
#define OFF_CHSUM 0      // [64]
#define OFF_CHSQ  64     // [64]
#define OFF_FEAT  256    // [16*64] pooled relu sums (pre-division)
#define OFF_Z     2048   // [16*256*256] z = sum_a g[a]*xh[px][a]

typedef __attribute__((ext_vector_type(8))) short bf16x8;
typedef __attribute__((ext_vector_type(4))) float f32x4;

union BFu { __hip_bfloat16 h; short s; };
union ABu { bf16x8 v; unsigned u[4]; };

__device__ __forceinline__ short bf_hi(float v, float& resid) {
    BFu u; u.h = __float2bfloat16(v);
    resid = v - __bfloat162float(u.h);
    return u.s;
}
__device__ __forceinline__ short bf_of(float v) {
    BFu u; u.h = __float2bfloat16(v);
    return u.s;
}

__global__ void k_init(float* __restrict__ ws) {
    int i = blockIdx.x * 256 + threadIdx.x;
    if (i < 1280) ws[i] = 0.f;
}

// z[px] = sum_a xh[px][a] / (band[a]*1e-6)   (SRF is rank-1: srf = p[b,c] * g[a])
__global__ __launch_bounds__(256) void k_z(const float* __restrict__ xh,
                                           float* __restrict__ ws) {
    __shared__ float s_x[256 * 31];
    __shared__ float s_g[32];
    const int t = threadIdx.x;
    const int blk = blockIdx.x;
    const size_t pix0 = (size_t)blk << 8;
    if (t < 31) {
        const float band = 400.f + (300.f * (float)t) / 31.f;
        s_g[t] = 1.f / (band * 1e-6f);
    }
    const float4* xg = (const float4*)(xh + pix0 * 31);
    float4* sx4 = (float4*)s_x;
#pragma unroll
    for (int i = 0; i < 8; ++i) {
        int idx = t + (i << 8);
        if (idx < 1984) sx4[idx] = xg[idx];
    }
    __syncthreads();
    float acc = 0.f;
    const float* px = s_x + t * 31;
#pragma unroll
    for (int a = 0; a < 31; ++a) acc = fmaf(px[a], s_g[a], acc);
    ws[OFF_Z + pix0 + t] = acc;
}

// Implicit-GEMM conv (split-bf16 MFMA, LDS-gathered A; verified r6/r7).
// Block: 4 waves = rows r0..r0+3, cols [128*ch2, 128*ch2+128) of image b.
// pan32[l][j] (stride 392): row l <-> global row r0-1+l; dword j <-> float (c0-1)*3+j,
// packed (hi_bf16 | lo_bf16<<16). Row 6 = ones row (A=1.0 for k>=27; k=27 = bias col).
// MODE 0: per-channel sum/sumsq.  MODE 1: stats computed inline from ws sums,
// then BN+ReLU and per-(b,c) pooled sum.
template <int MODE>
__global__ __launch_bounds__(256) void k_convg(const float* __restrict__ x,
                                               const float* __restrict__ cw,
                                               const float* __restrict__ cb,
                                               const float* __restrict__ bnw,
                                               const float* __restrict__ bnb,
                                               float* __restrict__ ws) {
    __shared__ unsigned pan32[7 * 392];
    __shared__ float red[4][4][16][2];
    const int t    = threadIdx.x;
    const int lane = t & 63;
    const int wv   = t >> 6;
    const int b    = blockIdx.y;
    const int r0   = blockIdx.x * 4;
    const int c0   = blockIdx.z * 128;
    const int mrow = lane & 15;
    const int s    = lane >> 4;

    // ---- stage 6 rows x 390 floats (border-predicated, coalesced), bf16 hi/lo packed
    {
        const float* __restrict__ xb = x + (size_t)b * (HH * WW * 3);
        const int g0 = c0 * 3 - 3;
        for (int e = t; e < 6 * 390; e += 256) {
            const int l = e / 390, j = e - l * 390;
            const int gr = r0 - 1 + l, gcf = g0 + j;
            const bool ok = ((unsigned)gr < 256u) && ((unsigned)gcf < 768u);
            int off = gr * 768 + gcf;
            off = ok ? off : 0;
            float v = xb[off];
            v = ok ? v : 0.f;
            float rs2;
            const unsigned hi = (unsigned short)bf_hi(v, rs2);
            const unsigned lo = (unsigned short)bf_of(rs2);
            pan32[l * 392 + j] = hi | (lo << 16);
        }
        for (int j = t; j < 392; j += 256) pan32[6 * 392 + j] = 0x3F80u;  // pack(1.0, 0)
    }

    // ---- B fragments (weights, k-permuted; k=27 = bias) + BN consts (MODE 1)
    bf16x8 bh[4], bl[4];
    float av[4], bvv[4];
#pragma unroll
    for (int n = 0; n < 4; ++n) {
        const int ch = n * 16 + mrow;
        if (MODE == 1) {
            const float invN = 1.f / 1048576.f;
            const float mu = ws[OFF_CHSUM + ch] * invN;
            const float vr = ws[OFF_CHSQ + ch] * invN - mu * mu;
            const float rs = rsqrtf(vr + 1e-5f);
            av[n]  = rs * bnw[ch];
            bvv[n] = bnb[ch] - mu * av[n];
        } else { av[n] = 0.f; bvv[n] = 0.f; }
#pragma unroll
        for (int e = 0; e < 8; ++e) {
            const int k = s * 8 + e;
            float w = 0.f;
            if (k < 27) {
                const int kh = (k >= 18) ? 2 : (k >= 9 ? 1 : 0);
                const int j  = k - kh * 9;
                const int kw2 = j / 3, ci = j - kw2 * 3;
                w = cw[ch * 27 + ci * 9 + kh * 3 + kw2];
            } else if (k == 27) {
                w = cb[ch];
            }
            float rs2;
            bh[n][e] = bf_hi(w, rs2);
            bl[n][e] = bf_of(rs2);
        }
    }

    // ---- per-lane gather offsets (dword units)
    int off8[8];
#pragma unroll
    for (int e = 0; e < 8; ++e) {
        const int k = s * 8 + e;
        if (k < 27) {
            const int kh = (k >= 18) ? 2 : (k >= 9 ? 1 : 0);
            off8[e] = (wv + kh) * 392 + (k - kh * 9);
        } else {
            off8[e] = 6 * 392 + (e - 3);   // ones row
        }
    }

    __syncthreads();

    float a0[4] = {0.f, 0.f, 0.f, 0.f};
    float a1[4] = {0.f, 0.f, 0.f, 0.f};

#define GATHER(W, CS)                                                  \
    {                                                                  \
        const int c3 = ((CS) * 16 + mrow) * 3;                         \
        W[0] = pan32[off8[0] + c3]; W[1] = pan32[off8[1] + c3];        \
        W[2] = pan32[off8[2] + c3]; W[3] = pan32[off8[3] + c3];        \
        W[4] = pan32[off8[4] + c3]; W[5] = pan32[off8[5] + c3];        \
        W[6] = pan32[off8[6] + c3]; W[7] = pan32[off8[7] + c3];        \
    }
#define COMPUTE(W)                                                     \
    {                                                                  \
        ABu ua, ul;                                                    \
        ua.u[0] = (W[0] & 0xFFFFu) | (W[1] << 16);                     \
        ua.u[1] = (W[2] & 0xFFFFu) | (W[3] << 16);                     \
        ua.u[2] = (W[4] & 0xFFFFu) | (W[5] << 16);                     \
        ua.u[3] = (W[6] & 0xFFFFu) | (W[7] << 16);                     \
        ul.u[0] = (W[0] >> 16) | (W[1] & 0xFFFF0000u);                 \
        ul.u[1] = (W[2] >> 16) | (W[3] & 0xFFFF0000u);                 \
        ul.u[2] = (W[4] >> 16) | (W[5] & 0xFFFF0000u);                 \
        ul.u[3] = (W[6] >> 16) | (W[7] & 0xFFFF0000u);                 \
        const bf16x8 ah = ua.v, al = ul.v;                             \
        _Pragma("unroll")                                              \
        for (int n = 0; n < 4; ++n) {                                  \
            f32x4 acc = {0.f, 0.f, 0.f, 0.f};                          \
            acc = __builtin_amdgcn_mfma_f32_16x16x32_bf16(ah, bl[n], acc, 0, 0, 0); \
            acc = __builtin_amdgcn_mfma_f32_16x16x32_bf16(al, bh[n], acc, 0, 0, 0); \
            acc = __builtin_amdgcn_mfma_f32_16x16x32_bf16(ah, bh[n], acc, 0, 0, 0); \
            _Pragma("unroll")                                          \
            for (int i = 0; i < 4; ++i) {                              \
                const float y = acc[i];                                \
                if (MODE == 0) { a0[n] += y; a1[n] = fmaf(y, y, a1[n]); } \
                else { a0[n] += fmaxf(fmaf(y, av[n], bvv[n]), 0.f); }  \
            }                                                          \
        }                                                              \
    }

    unsigned Wa[8], Wb[8];
    GATHER(Wa, 0)
    GATHER(Wb, 1) COMPUTE(Wa)
    GATHER(Wa, 2) COMPUTE(Wb)
    GATHER(Wb, 3) COMPUTE(Wa)
    GATHER(Wa, 4) COMPUTE(Wb)
    GATHER(Wb, 5) COMPUTE(Wa)
    GATHER(Wa, 6) COMPUTE(Wb)
    GATHER(Wb, 7) COMPUTE(Wa)
    COMPUTE(Wb)
#undef GATHER
#undef COMPUTE

    // ---- reduce over px (C rows): lanes l, l^16, l^32 share a C column
#pragma unroll
    for (int n = 0; n < 4; ++n) {
        a0[n] += __shfl_xor(a0[n], 16);
        a0[n] += __shfl_xor(a0[n], 32);
        if (MODE == 0) {
            a1[n] += __shfl_xor(a1[n], 16);
            a1[n] += __shfl_xor(a1[n], 32);
        }
    }
    if (lane < 16) {
#pragma unroll
        for (int n = 0; n < 4; ++n) {
            red[wv][n][lane][0] = a0[n];
            red[wv][n][lane][1] = (MODE == 0) ? a1[n] : 0.f;
        }
    }
    __syncthreads();
    if (t < 64) {
        const int n = t >> 4, m = t & 15;
        const float S = red[0][n][m][0] + red[1][n][m][0] + red[2][n][m][0] + red[3][n][m][0];
        if (MODE == 0) {
            const float Q = red[0][n][m][1] + red[1][n][m][1] + red[2][n][m][1] + red[3][n][m][1];
            atomicAdd(&ws[OFF_CHSUM + t], S);
            atomicAdd(&ws[OFF_CHSQ + t], Q);
        } else {
            atomicAdd(&ws[OFF_FEAT + b * 64 + t], S);
        }
    }
}

// out[px][c] = p[b][c] * z[px]; voltage net (fc + norm + sort + sin^2) fused per block.
__global__ __launch_bounds__(256) void k_final(const float* __restrict__ fcw,
                                               const float* __restrict__ fcb,
                                               const float* __restrict__ ws,
                                               float* __restrict__ out) {
    __shared__ float s_raw[5];
    __shared__ float sp[3];
    __shared__ float s_o[768];
    const int t = threadIdx.x;
    const int blk = blockIdx.x;
    const int b = blk >> 8;
    const size_t pix0 = (size_t)blk << 8;

    if (t < 5) {
        const float inv = 1.f / 65536.f;
        float a = fcb[t];
        for (int c = 0; c < 64; ++c)
            a = fmaf(fcw[t * 64 + c], ws[OFF_FEAT + b * 64 + c] * inv, a);
        s_raw[t] = a;
    }
    __syncthreads();
    if (t == 0) {
        float raw[5];
#pragma unroll
        for (int j = 0; j < 5; ++j) raw[j] = s_raw[j];
#define CS(i, j)                              \
        {                                     \
            float lo = fminf(raw[i], raw[j]); \
            float hi = fmaxf(raw[i], raw[j]); \
            raw[i] = lo;                      \
            raw[j] = hi;                      \
        }
        CS(0, 1) CS(3, 4) CS(2, 4) CS(2, 3) CS(0, 3) CS(0, 2) CS(1, 4) CS(1, 3) CS(1, 2)
#undef CS
        const float mn = raw[0], mx = raw[4];
        const float sc = 10.f / (mx - mn + 1e-8f);
#pragma unroll
        for (int c2 = 0; c2 < 3; ++c2) {
            const float v = (raw[1 + c2] - mn) * sc;
            const float sh = sinf(0.031415926535897934f / v);
            sp[c2] = sh * sh;
        }
    }
    __syncthreads();
    const float z = ws[OFF_Z + pix0 + t];
    s_o[t * 3 + 0] = sp[0] * z;
    s_o[t * 3 + 1] = sp[1] * z;
    s_o[t * 3 + 2] = sp[2] * z;
    __syncthreads();
    float* ob = out + pix0 * 3;
#pragma unroll
    for (int i = 0; i < 3; ++i) ob[t + (i << 8)] = s_o[t + (i << 8)];
}

extern "C" void kernel_launch(void* const* d_in, const int* in_sizes, int n_in,
                              void* d_out, int out_size, void* d_ws, size_t ws_size,
                              hipStream_t stream) {
    const float* x    = (const float*)d_in[0];
    const float* xhsi = (const float*)d_in[1];
    const float* cw   = (const float*)d_in[2];
    const float* cb   = (const float*)d_in[3];
    const float* bnw  = (const float*)d_in[4];
    const float* bnb  = (const float*)d_in[5];
    const float* fcw  = (const float*)d_in[6];
    const float* fcb  = (const float*)d_in[7];
    float* out = (float*)d_out;
    float* ws  = (float*)d_ws;

    hipLaunchKernelGGL(k_init, dim3(5), dim3(256), 0, stream, ws);
    hipLaunchKernelGGL(k_z, dim3(4096), dim3(256), 0, stream, xhsi, ws);
    hipLaunchKernelGGL((k_convg<0>), dim3(64, 16, 2), dim3(256), 0, stream,
                       x, cw, cb, bnw, bnb, ws);
    hipLaunchKernelGGL((k_convg<1>), dim3(64, 16, 2), dim3(256), 0, stream,
                       x, cw, cb, bnw, bnb, ws);
    hipLaunchKernelGGL(k_final, dim3(4096), dim3(256), 0, stream, fcw, fcb, ws, out);
}

// Round 10
// 102.588 us; speedup vs baseline: 1.2573x; 1.2573x over previous
//
#include <hip/hip_runtime.h>
#include <hip/hip_bf16.h>
#include <math.h>

#define BB 16
#define HH 256
#define WW 256

// ws layout in floats
#define OFF_CHSUM 0      // [64]
#define OFF_CHSQ  64     // [64]
#define OFF_FEAT  256    // [16*64] pooled relu sums (pre-division)

#define PAN_DW   (6 * 776)           // main panel: 6 rows x 776 dwords
#define TAIL_OFF PAN_DW              // tail records: 256 px x 12 dwords
#define LDS_DW   (PAN_DW + 256 * 12)

typedef __attribute__((ext_vector_type(8))) short bf16x8;
typedef __attribute__((ext_vector_type(4))) float f32x4;

union BFu { __hip_bfloat16 h; short s; };
union ABu { bf16x8 v; unsigned u[4]; };

__device__ __forceinline__ unsigned packsplit(float v) {
    BFu hi; hi.h = __float2bfloat16(v);
    float rs = v - __bfloat162float(hi.h);
    BFu lo; lo.h = __float2bfloat16(rs);
    return (unsigned)(unsigned short)hi.s | ((unsigned)(unsigned short)lo.s << 16);
}

__global__ void k_init(float* __restrict__ ws) {
    int i = blockIdx.x * 256 + threadIdx.x;
    if (i < 1280) ws[i] = 0.f;
}

// Implicit-GEMM conv, split-bf16 MFMA (r6-verified numerics), consecutive-dword K-order:
//  slice s in {0,1,2}: k = s*8+e  <-> tap (kh=s, jj=e)   [jj = kw*3+ci, window dword]
//  slice 3:            e in {0,1,2} <-> (kh=e, jj=8); e==3 <-> bias (A=1.0); e>=4 zero.
// Panel row l (0..5) = global row r0-1+l, dword j <-> input float (c0-1)*3+j... here
// full-width: pan[l*776 + j] = x[r0-1+l][float j-3]. A-gather for tile cs: lane(s<3)
// reads 8 consecutive dwords at (wv+s)*776 + (cs*16+mrow)*3  -> 4x ds_read2_b32.
// Tail record (per px c): {j8row0..j8row5, 0x3F80, 0,0,0,0,0}; lane s3 base = mrow*12+wv,
// reads dwords wv..wv+7, then W[3]=1.0,W[4..7]=0 via uniform selects.
// MODE 0: per-channel sum/sumsq of y.  MODE 1: stats inline from ws, BN FOLDED into
// B-frags (w'=av*w, bias'=av*cb+bvv), epilogue = relu+add, per-(b,c) pooled sums.
template <int MODE>
__global__ __launch_bounds__(256) void k_conv2(const float* __restrict__ x,
                                               const float* __restrict__ cw,
                                               const float* __restrict__ cb,
                                               const float* __restrict__ bnw,
                                               const float* __restrict__ bnb,
                                               float* __restrict__ ws) {
    __shared__ unsigned lds[LDS_DW];
    __shared__ float red[4][4][16][2];
    const int t    = threadIdx.x;
    const int lane = t & 63;
    const int wv   = t >> 6;
    const int b    = blockIdx.y;
    const int r0   = blockIdx.x * 4;
    const int mrow = lane & 15;
    const int s    = lane >> 4;
    const bool s3  = (s == 3);
    const float* __restrict__ xb = x + (size_t)b * (HH * WW * 3);

    // ---- stage main panel: 6 rows x 774 floats, border-predicated, bf16 hi/lo packed
    for (int e = t; e < 6 * 774; e += 256) {
        const int l = e / 774, j = e - l * 774;
        const int gr = r0 - 1 + l, gcf = j - 3;
        const bool ok = ((unsigned)gr < 256u) && ((unsigned)gcf < 768u);
        int off = gr * 768 + gcf;
        off = ok ? off : 0;
        float v = xb[off];
        v = ok ? v : 0.f;
        lds[l * 776 + j] = packsplit(v);
    }
    // ---- stage tail records: 256 x {j8 of rows 0..5, 1.0, zeros}
    for (int e = t; e < 256 * 12; e += 256) {
        const int c = e / 12, r = e - c * 12;
        unsigned val = 0u;
        if (r < 6) {
            const int gr = r0 - 1 + r, gcf = c * 3 + 5;   // col c+1, ch 2
            const bool ok = ((unsigned)gr < 256u) && (gcf < 768);
            int off = gr * 768 + gcf;
            off = ok ? off : 0;
            float v = xb[off];
            v = ok ? v : 0.f;
            val = packsplit(v);
        } else if (r == 6) {
            val = 0x3F80u;   // bf16 1.0 | lo 0
        }
        lds[TAIL_OFF + e] = val;
    }

    // ---- stats (MODE 1) + B fragments in the (s,e) k-order; BN folded in MODE 1
    float av[4], bvv[4];
    bf16x8 bh[4], bl[4];
#pragma unroll
    for (int n = 0; n < 4; ++n) {
        const int ch = n * 16 + mrow;
        if (MODE == 1) {
            const float invN = 1.f / 1048576.f;
            const float mu = ws[OFF_CHSUM + ch] * invN;
            const float vr = ws[OFF_CHSQ + ch] * invN - mu * mu;
            const float rs = rsqrtf(vr + 1e-5f);
            av[n]  = rs * bnw[ch];
            bvv[n] = bnb[ch] - mu * av[n];
        } else { av[n] = 1.f; bvv[n] = 0.f; }
#pragma unroll
        for (int e = 0; e < 8; ++e) {
            float w = 0.f;
            if (!s3) {
                w = cw[ch * 27 + (e % 3) * 9 + s * 3 + (e / 3)];   // tap (kh=s, jj=e)
            } else if (e < 3) {
                w = cw[ch * 27 + 2 * 9 + e * 3 + 2];               // (kh=e, jj=8)
            } else if (e == 3) {
                w = cb[ch];                                        // bias column
            }
            if (MODE == 1) {
                w *= av[n];
                if (s3 && e == 3) w += bvv[n];                     // av*cb + bvv
            }
            BFu hi; hi.h = __float2bfloat16(w);
            const float rs2 = w - __bfloat162float(hi.h);
            BFu lo; lo.h = __float2bfloat16(rs2);
            bh[n][e] = hi.s;
            bl[n][e] = lo.s;
        }
    }

    // ---- per-lane gather base/delta (dword units)
    const int gbase  = s3 ? (TAIL_OFF + mrow * 12 + wv) : ((wv + s) * 776 + mrow * 3);
    const int gdelta = s3 ? 192 : 48;

    __syncthreads();

    float a0[4] = {0.f, 0.f, 0.f, 0.f};
    float a1[4] = {0.f, 0.f, 0.f, 0.f};

#define GATHER(W, CS)                                                   \
    {                                                                   \
        const int ba = gbase + (CS) * gdelta;                           \
        W[0] = lds[ba + 0]; W[1] = lds[ba + 1];                         \
        W[2] = lds[ba + 2]; W[3] = lds[ba + 3];                         \
        W[4] = lds[ba + 4]; W[5] = lds[ba + 5];                         \
        W[6] = lds[ba + 6]; W[7] = lds[ba + 7];                         \
        W[3] = s3 ? 0x3F80u : W[3];                                     \
        W[4] = s3 ? 0u : W[4];  W[5] = s3 ? 0u : W[5];                  \
        W[6] = s3 ? 0u : W[6];  W[7] = s3 ? 0u : W[7];                  \
    }
#define COMPUTE(W)                                                      \
    {                                                                   \
        ABu ua, ul;                                                     \
        ua.u[0] = (W[0] & 0xFFFFu) | (W[1] << 16);                      \
        ua.u[1] = (W[2] & 0xFFFFu) | (W[3] << 16);                      \
        ua.u[2] = (W[4] & 0xFFFFu) | (W[5] << 16);                      \
        ua.u[3] = (W[6] & 0xFFFFu) | (W[7] << 16);                      \
        ul.u[0] = (W[0] >> 16) | (W[1] & 0xFFFF0000u);                  \
        ul.u[1] = (W[2] >> 16) | (W[3] & 0xFFFF0000u);                  \
        ul.u[2] = (W[4] >> 16) | (W[5] & 0xFFFF0000u);                  \
        ul.u[3] = (W[6] >> 16) | (W[7] & 0xFFFF0000u);                  \
        const bf16x8 ah = ua.v, al = ul.v;                              \
        _Pragma("unroll")                                               \
        for (int n = 0; n < 4; ++n) {                                   \
            f32x4 acc = {0.f, 0.f, 0.f, 0.f};                           \
            acc = __builtin_amdgcn_mfma_f32_16x16x32_bf16(ah, bl[n], acc, 0, 0, 0); \
            acc = __builtin_amdgcn_mfma_f32_16x16x32_bf16(al, bh[n], acc, 0, 0, 0); \
            acc = __builtin_amdgcn_mfma_f32_16x16x32_bf16(ah, bh[n], acc, 0, 0, 0); \
            _Pragma("unroll")                                           \
            for (int i = 0; i < 4; ++i) {                               \
                const float y = acc[i];                                 \
                if (MODE == 0) { a0[n] += y; a1[n] = fmaf(y, y, a1[n]); } \
                else { a0[n] += fmaxf(y, 0.f); }                        \
            }                                                           \
        }                                                               \
    }

    {
        unsigned Wa[8], Wb[8];
        GATHER(Wa, 0)
        GATHER(Wb, 1)  COMPUTE(Wa)
        GATHER(Wa, 2)  COMPUTE(Wb)
        GATHER(Wb, 3)  COMPUTE(Wa)
        GATHER(Wa, 4)  COMPUTE(Wb)
        GATHER(Wb, 5)  COMPUTE(Wa)
        GATHER(Wa, 6)  COMPUTE(Wb)
        GATHER(Wb, 7)  COMPUTE(Wa)
        GATHER(Wa, 8)  COMPUTE(Wb)
        GATHER(Wb, 9)  COMPUTE(Wa)
        GATHER(Wa, 10) COMPUTE(Wb)
        GATHER(Wb, 11) COMPUTE(Wa)
        GATHER(Wa, 12) COMPUTE(Wb)
        GATHER(Wb, 13) COMPUTE(Wa)
        GATHER(Wa, 14) COMPUTE(Wb)
        GATHER(Wb, 15) COMPUTE(Wa)
        COMPUTE(Wb)
    }
#undef GATHER
#undef COMPUTE

    // ---- reduce over px (C rows): lanes l, l^16, l^32 share a C column
#pragma unroll
    for (int n = 0; n < 4; ++n) {
        a0[n] += __shfl_xor(a0[n], 16);
        a0[n] += __shfl_xor(a0[n], 32);
        if (MODE == 0) {
            a1[n] += __shfl_xor(a1[n], 16);
            a1[n] += __shfl_xor(a1[n], 32);
        }
    }
    if (lane < 16) {
#pragma unroll
        for (int n = 0; n < 4; ++n) {
            red[wv][n][lane][0] = a0[n];
            red[wv][n][lane][1] = (MODE == 0) ? a1[n] : 0.f;
        }
    }
    __syncthreads();
    if (t < 64) {
        const int n = t >> 4, m = t & 15;
        const float S = red[0][n][m][0] + red[1][n][m][0] + red[2][n][m][0] + red[3][n][m][0];
        if (MODE == 0) {
            const float Q = red[0][n][m][1] + red[1][n][m][1] + red[2][n][m][1] + red[3][n][m][1];
            atomicAdd(&ws[OFF_CHSUM + t], S);
            atomicAdd(&ws[OFF_CHSQ + t], Q);
        } else {
            atomicAdd(&ws[OFF_FEAT + b * 64 + t], S);
        }
    }
}

// out[px][c] = p[b][c] * z[px], z = sum_a xh[px][a]/(band[a]*1e-6) computed inline.
// Voltage net (fc + norm + sort + sin^2) recomputed per block (trivial).
__global__ __launch_bounds__(256) void k_final(const float* __restrict__ fcw,
                                               const float* __restrict__ fcb,
                                               const float* __restrict__ ws,
                                               const float* __restrict__ xh,
                                               float* __restrict__ out) {
    __shared__ float s_x[256 * 31];
    __shared__ float s_g[32];
    __shared__ float s_raw[5];
    __shared__ float sp[3];
    __shared__ float s_o[768];
    const int t = threadIdx.x;
    const int blk = blockIdx.x;
    const int b = blk >> 8;
    const size_t pix0 = (size_t)blk << 8;

    if (t < 31) {
        const float band = 400.f + (300.f * (float)t) / 31.f;
        s_g[t] = 1.f / (band * 1e-6f);
    }
    if (t >= 32 && t < 37) {
        const int j = t - 32;
        const float inv = 1.f / 65536.f;
        float a = fcb[j];
        for (int c = 0; c < 64; ++c)
            a = fmaf(fcw[j * 64 + c], ws[OFF_FEAT + b * 64 + c] * inv, a);
        s_raw[j] = a;
    }
    const float4* xg = (const float4*)(xh + pix0 * 31);
    float4* sx4 = (float4*)s_x;
#pragma unroll
    for (int i = 0; i < 8; ++i) {
        int idx = t + (i << 8);
        if (idx < 1984) sx4[idx] = xg[idx];
    }
    __syncthreads();
    if (t == 0) {
        float raw[5];
#pragma unroll
        for (int j = 0; j < 5; ++j) raw[j] = s_raw[j];
#define CS(i, j)                              \
        {                                     \
            float lo = fminf(raw[i], raw[j]); \
            float hi = fmaxf(raw[i], raw[j]); \
            raw[i] = lo;                      \
            raw[j] = hi;                      \
        }
        CS(0, 1) CS(3, 4) CS(2, 4) CS(2, 3) CS(0, 3) CS(0, 2) CS(1, 4) CS(1, 3) CS(1, 2)
#undef CS
        const float mn = raw[0], mx = raw[4];
        const float sc = 10.f / (mx - mn + 1e-8f);
#pragma unroll
        for (int c2 = 0; c2 < 3; ++c2) {
            const float v = (raw[1 + c2] - mn) * sc;
            const float sh = sinf(0.031415926535897934f / v);
            sp[c2] = sh * sh;
        }
    }
    __syncthreads();
    float z = 0.f;
    const float* px = s_x + t * 31;
#pragma unroll
    for (int a = 0; a < 31; ++a) z = fmaf(px[a], s_g[a], z);
    s_o[t * 3 + 0] = sp[0] * z;
    s_o[t * 3 + 1] = sp[1] * z;
    s_o[t * 3 + 2] = sp[2] * z;
    __syncthreads();
    float* ob = out + pix0 * 3;
#pragma unroll
    for (int i = 0; i < 3; ++i) ob[t + (i << 8)] = s_o[t + (i << 8)];
}

extern "C" void kernel_launch(void* const* d_in, const int* in_sizes, int n_in,
                              void* d_out, int out_size, void* d_ws, size_t ws_size,
                              hipStream_t stream) {
    const float* x    = (const float*)d_in[0];
    const float* xhsi = (const float*)d_in[1];
    const float* cw   = (const float*)d_in[2];
    const float* cb   = (const float*)d_in[3];
    const float* bnw  = (const float*)d_in[4];
    const float* bnb  = (const float*)d_in[5];
    const float* fcw  = (const float*)d_in[6];
    const float* fcb  = (const float*)d_in[7];
    float* out = (float*)d_out;
    float* ws  = (float*)d_ws;

    hipLaunchKernelGGL(k_init, dim3(5), dim3(256), 0, stream, ws);
    hipLaunchKernelGGL((k_conv2<0>), dim3(64, 16), dim3(256), 0, stream,
                       x, cw, cb, bnw, bnb, ws);
    hipLaunchKernelGGL((k_conv2<1>), dim3(64, 16), dim3(256), 0, stream,
                       x, cw, cb, bnw, bnb, ws);
    hipLaunchKernelGGL(k_final, dim3(4096), dim3(256), 0, stream, fcw, fcb, ws, xhsi, out);
}

// Round 11
// 92.149 us; speedup vs baseline: 1.3997x; 1.1133x over previous
//
#include <hip/hip_runtime.h>
#include <hip/hip_bf16.h>
#include <math.h>

#define BB 16
#define HH 256
#define WW 256

// ws layout in floats
#define OFF_CHSUM 0      // [64]
#define OFF_CHSQ  64     // [64]
#define OFF_FEAT  256    // [16*64] pooled relu sums (pre-division)

#define PAN_DW (7 * 776)   // 6 data rows + 1 "ones" row

typedef __attribute__((ext_vector_type(8))) short bf16x8;
typedef __attribute__((ext_vector_type(4))) float f32x4;

union BFu { __hip_bfloat16 h; short s; };
union ABu { bf16x8 v; unsigned u[4]; };

__device__ __forceinline__ unsigned packsplit(float v) {
    BFu hi; hi.h = __float2bfloat16(v);
    float rs = v - __bfloat162float(hi.h);
    BFu lo; lo.h = __float2bfloat16(rs);
    return (unsigned)(unsigned short)hi.s | ((unsigned)(unsigned short)lo.s << 16);
}

__global__ void k_init(float* __restrict__ ws) {
    int i = blockIdx.x * 256 + threadIdx.x;
    if (i < 1280) ws[i] = 0.f;
}

// Implicit-GEMM conv, split-bf16 MFMA (r6/r7/r10-verified numerics).
// K-order: slice s in {0,1,2}: k=s*8+e <-> tap (kh=s, jj=e) [jj=kw*3+ci];
//          slice 3: e<3 <-> (kh=e, jj=8); e==3 <-> bias (A=1.0); e>=4 A=1,B=0.
// pan[l*776+j]: row l (0..5) = global row r0-1+l, dword j = packsplit(x float j-3);
// row 6 = packsplit(1.0) everywhere (bias/neutral slots; c3-advance stays in-row).
// A-gather: 8 per-lane-offset ds_read_b32 at off8[e]+c3 (no selects, no tail array).
// KEY r11 FIX: cw/cb staged to LDS coalesced (s_w/s_b); B-frags read from LDS —
// removes ~2048 scattered global lane-loads per wave (the TA-throughput bottleneck).
// MODE 0: per-channel sum/sumsq of y.  MODE 1: stats inline from ws, BN folded into
// B-frags (w'=av*w, bias'=av*cb+bvv), epilogue relu+add, per-(b,c) pooled sums.
template <int MODE>
__global__ __launch_bounds__(256) void k_conv3(const float* __restrict__ x,
                                               const float* __restrict__ cw,
                                               const float* __restrict__ cb,
                                               const float* __restrict__ bnw,
                                               const float* __restrict__ bnb,
                                               float* __restrict__ ws) {
    __shared__ unsigned lds[PAN_DW];
    __shared__ float s_w[1728];
    __shared__ float s_b[64];
    __shared__ float red[4][4][16][2];
    const int t    = threadIdx.x;
    const int lane = t & 63;
    const int wv   = t >> 6;
    const int b    = blockIdx.y;
    const int r0   = blockIdx.x * 4;
    const int mrow = lane & 15;
    const int s    = lane >> 4;
    const bool s3  = (s == 3);
    const float* __restrict__ xb = x + (size_t)b * (HH * WW * 3);

    // ---- stage weights/bias to LDS (coalesced; kills the scattered B-frag gather)
    for (int i = t; i < 1728; i += 256) s_w[i] = cw[i];
    if (t < 64) s_b[t] = cb[t];

    // ---- stage main panel: 6 rows x 774 floats, border-predicated, bf16 hi/lo packed
    for (int e = t; e < 6 * 774; e += 256) {
        const int l = e / 774, j = e - l * 774;
        const int gr = r0 - 1 + l, gcf = j - 3;
        const bool ok = ((unsigned)gr < 256u) && ((unsigned)gcf < 768u);
        int off = gr * 768 + gcf;
        off = ok ? off : 0;
        float v = xb[off];
        v = ok ? v : 0.f;
        lds[l * 776 + j] = packsplit(v);
    }
    for (int j = t; j < 776; j += 256) lds[6 * 776 + j] = 0x3F80u;  // pack(1.0, 0)

    // ---- stats (MODE 1): coalesced global reads, trivial
    float av[4], bvv[4];
#pragma unroll
    for (int n = 0; n < 4; ++n) {
        const int ch = n * 16 + mrow;
        if (MODE == 1) {
            const float invN = 1.f / 1048576.f;
            const float mu = ws[OFF_CHSUM + ch] * invN;
            const float vr = ws[OFF_CHSQ + ch] * invN - mu * mu;
            const float rs = rsqrtf(vr + 1e-5f);
            av[n]  = rs * bnw[ch];
            bvv[n] = bnb[ch] - mu * av[n];
        } else { av[n] = 1.f; bvv[n] = 0.f; }
    }

    // ---- per-lane gather offsets (dword units); c3 advance stays in-row for all
    int off8[8];
#pragma unroll
    for (int e = 0; e < 8; ++e) {
        if (!s3)        off8[e] = (wv + s) * 776 + e;           // tap (kh=s, jj=e)
        else if (e < 3) off8[e] = (wv + e) * 776 + 8;           // tap (kh=e, jj=8)
        else            off8[e] = 6 * 776 + e;                  // ones row
    }
    const int mrow3 = mrow * 3;

    __syncthreads();

    // ---- B fragments from LDS (broadcast-class reads) with BN fold in MODE 1
    bf16x8 bh[4], bl[4];
#pragma unroll
    for (int n = 0; n < 4; ++n) {
        const int ch = n * 16 + mrow;
#pragma unroll
        for (int e = 0; e < 8; ++e) {
            float w = 0.f;
            if (!s3) {
                w = s_w[ch * 27 + (e % 3) * 9 + s * 3 + (e / 3)];
            } else if (e < 3) {
                w = s_w[ch * 27 + 18 + e * 3 + 2];
            } else if (e == 3) {
                w = s_b[ch];
            }
            if (MODE == 1) {
                w *= av[n];
                if (s3 && e == 3) w += bvv[n];
            }
            BFu hi; hi.h = __float2bfloat16(w);
            const float rs2 = w - __bfloat162float(hi.h);
            BFu lo; lo.h = __float2bfloat16(rs2);
            bh[n][e] = hi.s;
            bl[n][e] = lo.s;
        }
    }

    float a0[4] = {0.f, 0.f, 0.f, 0.f};
    float a1[4] = {0.f, 0.f, 0.f, 0.f};

#define GATHER(W, CS)                                                   \
    {                                                                   \
        const int c3 = (CS) * 48 + mrow3;                               \
        W[0] = lds[off8[0] + c3]; W[1] = lds[off8[1] + c3];             \
        W[2] = lds[off8[2] + c3]; W[3] = lds[off8[3] + c3];             \
        W[4] = lds[off8[4] + c3]; W[5] = lds[off8[5] + c3];             \
        W[6] = lds[off8[6] + c3]; W[7] = lds[off8[7] + c3];             \
    }
#define COMPUTE(W)                                                      \
    {                                                                   \
        ABu ua, ul;                                                     \
        ua.u[0] = (W[0] & 0xFFFFu) | (W[1] << 16);                      \
        ua.u[1] = (W[2] & 0xFFFFu) | (W[3] << 16);                      \
        ua.u[2] = (W[4] & 0xFFFFu) | (W[5] << 16);                      \
        ua.u[3] = (W[6] & 0xFFFFu) | (W[7] << 16);                      \
        ul.u[0] = (W[0] >> 16) | (W[1] & 0xFFFF0000u);                  \
        ul.u[1] = (W[2] >> 16) | (W[3] & 0xFFFF0000u);                  \
        ul.u[2] = (W[4] >> 16) | (W[5] & 0xFFFF0000u);                  \
        ul.u[3] = (W[6] >> 16) | (W[7] & 0xFFFF0000u);                  \
        const bf16x8 ah = ua.v, al = ul.v;                              \
        _Pragma("unroll")                                               \
        for (int n = 0; n < 4; ++n) {                                   \
            f32x4 acc = {0.f, 0.f, 0.f, 0.f};                           \
            acc = __builtin_amdgcn_mfma_f32_16x16x32_bf16(ah, bl[n], acc, 0, 0, 0); \
            acc = __builtin_amdgcn_mfma_f32_16x16x32_bf16(al, bh[n], acc, 0, 0, 0); \
            acc = __builtin_amdgcn_mfma_f32_16x16x32_bf16(ah, bh[n], acc, 0, 0, 0); \
            _Pragma("unroll")                                           \
            for (int i = 0; i < 4; ++i) {                               \
                const float y = acc[i];                                 \
                if (MODE == 0) { a0[n] += y; a1[n] = fmaf(y, y, a1[n]); } \
                else { a0[n] += fmaxf(y, 0.f); }                        \
            }                                                           \
        }                                                               \
    }

    {
        unsigned Wa[8], Wb[8];
        GATHER(Wa, 0)
        GATHER(Wb, 1)  COMPUTE(Wa)
        GATHER(Wa, 2)  COMPUTE(Wb)
        GATHER(Wb, 3)  COMPUTE(Wa)
        GATHER(Wa, 4)  COMPUTE(Wb)
        GATHER(Wb, 5)  COMPUTE(Wa)
        GATHER(Wa, 6)  COMPUTE(Wb)
        GATHER(Wb, 7)  COMPUTE(Wa)
        GATHER(Wa, 8)  COMPUTE(Wb)
        GATHER(Wb, 9)  COMPUTE(Wa)
        GATHER(Wa, 10) COMPUTE(Wb)
        GATHER(Wb, 11) COMPUTE(Wa)
        GATHER(Wa, 12) COMPUTE(Wb)
        GATHER(Wb, 13) COMPUTE(Wa)
        GATHER(Wa, 14) COMPUTE(Wb)
        GATHER(Wb, 15) COMPUTE(Wa)
        COMPUTE(Wb)
    }
#undef GATHER
#undef COMPUTE

    // ---- reduce over px (C rows): lanes l, l^16, l^32 share a C column
#pragma unroll
    for (int n = 0; n < 4; ++n) {
        a0[n] += __shfl_xor(a0[n], 16);
        a0[n] += __shfl_xor(a0[n], 32);
        if (MODE == 0) {
            a1[n] += __shfl_xor(a1[n], 16);
            a1[n] += __shfl_xor(a1[n], 32);
        }
    }
    if (lane < 16) {
#pragma unroll
        for (int n = 0; n < 4; ++n) {
            red[wv][n][lane][0] = a0[n];
            red[wv][n][lane][1] = (MODE == 0) ? a1[n] : 0.f;
        }
    }
    __syncthreads();
    if (t < 64) {
        const int n = t >> 4, m = t & 15;
        const float S = red[0][n][m][0] + red[1][n][m][0] + red[2][n][m][0] + red[3][n][m][0];
        if (MODE == 0) {
            const float Q = red[0][n][m][1] + red[1][n][m][1] + red[2][n][m][1] + red[3][n][m][1];
            atomicAdd(&ws[OFF_CHSUM + t], S);
            atomicAdd(&ws[OFF_CHSQ + t], Q);
        } else {
            atomicAdd(&ws[OFF_FEAT + b * 64 + t], S);
        }
    }
}

// out[px][c] = p[b][c] * z[px], z = sum_a xh[px][a]/(band[a]*1e-6) computed inline.
// Voltage net (fc + norm + sort + sin^2) recomputed per block (trivial).
__global__ __launch_bounds__(256) void k_final(const float* __restrict__ fcw,
                                               const float* __restrict__ fcb,
                                               const float* __restrict__ ws,
                                               const float* __restrict__ xh,
                                               float* __restrict__ out) {
    __shared__ float s_x[256 * 31];
    __shared__ float s_g[32];
    __shared__ float s_raw[5];
    __shared__ float sp[3];
    __shared__ float s_o[768];
    const int t = threadIdx.x;
    const int blk = blockIdx.x;
    const int b = blk >> 8;
    const size_t pix0 = (size_t)blk << 8;

    if (t < 31) {
        const float band = 400.f + (300.f * (float)t) / 31.f;
        s_g[t] = 1.f / (band * 1e-6f);
    }
    if (t >= 32 && t < 37) {
        const int j = t - 32;
        const float inv = 1.f / 65536.f;
        float a = fcb[j];
        for (int c = 0; c < 64; ++c)
            a = fmaf(fcw[j * 64 + c], ws[OFF_FEAT + b * 64 + c] * inv, a);
        s_raw[j] = a;
    }
    const float4* xg = (const float4*)(xh + pix0 * 31);
    float4* sx4 = (float4*)s_x;
#pragma unroll
    for (int i = 0; i < 8; ++i) {
        int idx = t + (i << 8);
        if (idx < 1984) sx4[idx] = xg[idx];
    }
    __syncthreads();
    if (t == 0) {
        float raw[5];
#pragma unroll
        for (int j = 0; j < 5; ++j) raw[j] = s_raw[j];
#define CS(i, j)                              \
        {                                     \
            float lo = fminf(raw[i], raw[j]); \
            float hi = fmaxf(raw[i], raw[j]); \
            raw[i] = lo;                      \
            raw[j] = hi;                      \
        }
        CS(0, 1) CS(3, 4) CS(2, 4) CS(2, 3) CS(0, 3) CS(0, 2) CS(1, 4) CS(1, 3) CS(1, 2)
#undef CS
        const float mn = raw[0], mx = raw[4];
        const float sc = 10.f / (mx - mn + 1e-8f);
#pragma unroll
        for (int c2 = 0; c2 < 3; ++c2) {
            const float v = (raw[1 + c2] - mn) * sc;
            const float sh = sinf(0.031415926535897934f / v);
            sp[c2] = sh * sh;
        }
    }
    __syncthreads();
    float z = 0.f;
    const float* px = s_x + t * 31;
#pragma unroll
    for (int a = 0; a < 31; ++a) z = fmaf(px[a], s_g[a], z);
    s_o[t * 3 + 0] = sp[0] * z;
    s_o[t * 3 + 1] = sp[1] * z;
    s_o[t * 3 + 2] = sp[2] * z;
    __syncthreads();
    float* ob = out + pix0 * 3;
#pragma unroll
    for (int i = 0; i < 3; ++i) ob[t + (i << 8)] = s_o[t + (i << 8)];
}

extern "C" void kernel_launch(void* const* d_in, const int* in_sizes, int n_in,
                              void* d_out, int out_size, void* d_ws, size_t ws_size,
                              hipStream_t stream) {
    const float* x    = (const float*)d_in[0];
    const float* xhsi = (const float*)d_in[1];
    const float* cw   = (const float*)d_in[2];
    const float* cb   = (const float*)d_in[3];
    const float* bnw  = (const float*)d_in[4];
    const float* bnb  = (const float*)d_in[5];
    const float* fcw  = (const float*)d_in[6];
    const float* fcb  = (const float*)d_in[7];
    float* out = (float*)d_out;
    float* ws  = (float*)d_ws;

    hipLaunchKernelGGL(k_init, dim3(5), dim3(256), 0, stream, ws);
    hipLaunchKernelGGL((k_conv3<0>), dim3(64, 16), dim3(256), 0, stream,
                       x, cw, cb, bnw, bnb, ws);
    hipLaunchKernelGGL((k_conv3<1>), dim3(64, 16), dim3(256), 0, stream,
                       x, cw, cb, bnw, bnb, ws);
    hipLaunchKernelGGL(k_final, dim3(4096), dim3(256), 0, stream, fcw, fcb, ws, xhsi, out);
}